// Round 3
// baseline (2942.236 us; speedup 1.0000x reference)
//
#include <hip/hip_runtime.h>
#include <cstddef>
#include <cstdint>

namespace {

constexpr int NPROT = 100000;
constexpr int EPROT = 1600000;
constexpr int NLIG  = 5000;
constexpr int ELIG  = 80000;

// ---------------- CSR construction ----------------

__global__ void hist_kernel(const int* __restrict__ dst, int* __restrict__ cnt, int e) {
  int i = blockIdx.x * 256 + threadIdx.x;
  if (i < e) atomicAdd(&cnt[dst[i]], 1);
}

// per-block (1024 elems) exclusive scan; also computes nrm = max(deg,1)^-0.5
__global__ void scan1_kernel(const int* __restrict__ cnt, int* __restrict__ rp,
                             int* __restrict__ bsum, float* __restrict__ nrm, int n) {
  __shared__ int wsum[4];
  int t = threadIdx.x;
  int base = blockIdx.x * 1024 + t * 4;
  int v0 = 0, v1 = 0, v2 = 0, v3 = 0;
  if (base + 3 < n) {
    int4 val = *(const int4*)(cnt + base);
    v0 = val.x; v1 = val.y; v2 = val.z; v3 = val.w;
  } else if (base < n) {
    v0 = cnt[base];
    if (base + 1 < n) v1 = cnt[base + 1];
    if (base + 2 < n) v2 = cnt[base + 2];
  }
  if (base < n)     nrm[base]     = 1.0f / sqrtf(fmaxf((float)v0, 1.0f));
  if (base + 1 < n) nrm[base + 1] = 1.0f / sqrtf(fmaxf((float)v1, 1.0f));
  if (base + 2 < n) nrm[base + 2] = 1.0f / sqrtf(fmaxf((float)v2, 1.0f));
  if (base + 3 < n) nrm[base + 3] = 1.0f / sqrtf(fmaxf((float)v3, 1.0f));
  int ts = v0 + v1 + v2 + v3;
  int lane = t & 63, wv = t >> 6;
  int incl = ts;
  #pragma unroll
  for (int off = 1; off < 64; off <<= 1) {
    int o = __shfl_up(incl, off, 64);
    if (lane >= off) incl += o;
  }
  if (lane == 63) wsum[wv] = incl;
  __syncthreads();
  int woff = 0;
  #pragma unroll
  for (int i = 0; i < 4; ++i) if (i < wv) woff += wsum[i];
  int excl = woff + incl - ts;
  int o0 = excl, o1 = o0 + v0, o2 = o1 + v1, o3 = o2 + v2;
  if (base + 3 < n) {
    *(int4*)(rp + base) = make_int4(o0, o1, o2, o3);
  } else if (base < n) {
    rp[base] = o0;
    if (base + 1 < n) rp[base + 1] = o1;
    if (base + 2 < n) rp[base + 2] = o2;
  }
  if (t == 255) bsum[blockIdx.x] = woff + incl;  // block total
}

// exclusive scan of <=256 block sums; writes grand total to rp[n]
__global__ void scan2_kernel(int* __restrict__ bsum, int nb, int* __restrict__ rp_end) {
  __shared__ int s[256];
  int t = threadIdx.x;
  int v = (t < nb) ? bsum[t] : 0;
  s[t] = v;
  __syncthreads();
  int val = v;
  for (int off = 1; off < 256; off <<= 1) {
    int add = (t >= off) ? s[t - off] : 0;
    __syncthreads();
    val += add;
    s[t] = val;
    __syncthreads();
  }
  if (t < nb) bsum[t] = val - v;  // exclusive
  if (t == 255) *rp_end = val;    // total
}

__global__ void scan3_kernel(int* __restrict__ rp, const int* __restrict__ bsum, int n) {
  int i = blockIdx.x * 256 + threadIdx.x;
  if (i < n) rp[i] += bsum[i >> 10];
}

__global__ void scatter_kernel(const int* __restrict__ src, const int* __restrict__ dst,
                               const int* __restrict__ rp, int* __restrict__ cur,
                               int* __restrict__ col, int e) {
  int i = blockIdx.x * 256 + threadIdx.x;
  if (i < e) {
    int d = dst[i];
    int p = rp[d] + atomicAdd(&cur[d], 1);
    col[p] = src[i];
  }
}

// ---------------- GNN kernels ----------------
// Carry g_k = norm .* h_k.  Hop: s_k[v] = sum_{e: dst=v} g_{k-1}[src[e]]
//   h_k = norm .* s_k ;  g_k = norm^2 .* s_k
// y = b + sum_k h_k @ W[k*din:(k+1)*din]

// k=0: read x, write g_0 = x*nrm, y = bias + x @ W_0
template<int DIN, int DOUT>
__global__ void init_gemm_kernel(const float* __restrict__ x, const float* __restrict__ nrm,
                                 const float* __restrict__ W, const float* __restrict__ bias,
                                 float* __restrict__ gout, float* __restrict__ y, int n) {
  __shared__ float h[4][DIN];
  int wv = threadIdx.x >> 6, lane = threadIdx.x & 63;
  int v = blockIdx.x * 4 + wv;
  bool ok = (v < n);
  if (ok) {
    float nm = nrm[v];
    const float* xr = x + (size_t)v * DIN;
    for (int f = lane; f < DIN; f += 64) {
      float s = xr[f];
      h[wv][f] = s;
      gout[(size_t)v * DIN + f] = s * nm;
    }
  }
  __syncthreads();
  if (ok && lane < DOUT) {
    float acc = bias[lane];
    const float* Wk = W + lane;
    #pragma unroll 2
    for (int f = 0; f < DIN; ++f) acc += h[wv][f] * Wk[(size_t)f * DOUT];
    y[(size_t)v * DOUT + lane] = acc;
  }
}

// k>=1: fused gather + scale + (optional g-write) + GEMM accumulate.
// gin is immutable input (g_{k-1}); gout (g_k) is a DIFFERENT buffer (ping-pong).
// FINAL: relu + row-l2norm in-register, write X instead of y.
template<int DIN, int DOUT, bool WRITEG, bool FINAL>
__global__ void fused_hop_kernel(const float* __restrict__ gin, const int* __restrict__ rp,
                                 const int* __restrict__ col, const float* __restrict__ nrm,
                                 const float* __restrict__ W, float* __restrict__ gout,
                                 float* __restrict__ y, float* __restrict__ Xout,
                                 int k, int n) {
  __shared__ float h[4][DIN];
  int wv = threadIdx.x >> 6, lane = threadIdx.x & 63;
  int v = blockIdx.x * 4 + wv;
  bool ok = (v < n);
  if (ok) {
    int beg = rp[v], end = rp[v + 1];
    float a0 = 0.f, a1 = 0.f, b0 = 0.f, b1 = 0.f;
    float c0 = 0.f, c1 = 0.f, d0 = 0.f, d1 = 0.f;
    int e = beg;
    for (; e + 4 <= end; e += 4) {
      int s0 = col[e], s1 = col[e + 1], s2 = col[e + 2], s3 = col[e + 3];
      const float* r0 = gin + (size_t)s0 * DIN;
      const float* r1 = gin + (size_t)s1 * DIN;
      const float* r2 = gin + (size_t)s2 * DIN;
      const float* r3 = gin + (size_t)s3 * DIN;
      if (lane < DIN) { a0 += r0[lane]; b0 += r1[lane]; c0 += r2[lane]; d0 += r3[lane]; }
      if (DIN > 64) {
        if (lane + 64 < DIN) { a1 += r0[lane + 64]; b1 += r1[lane + 64]; c1 += r2[lane + 64]; d1 += r3[lane + 64]; }
      }
    }
    for (; e < end; ++e) {
      int s0 = col[e];
      const float* r0 = gin + (size_t)s0 * DIN;
      if (lane < DIN) a0 += r0[lane];
      if (DIN > 64) { if (lane + 64 < DIN) a1 += r0[lane + 64]; }
    }
    a0 += b0 + c0 + d0;
    a1 += b1 + c1 + d1;
    float nm = nrm[v];
    float h0 = a0 * nm, h1 = a1 * nm;
    if (lane < DIN) h[wv][lane] = h0;
    if (DIN > 64) { if (lane + 64 < DIN) h[wv][lane + 64] = h1; }
    if (WRITEG) {
      float* go = gout + (size_t)v * DIN;
      if (lane < DIN) go[lane] = h0 * nm;
      if (DIN > 64) { if (lane + 64 < DIN) go[lane + 64] = h1 * nm; }
    }
  }
  __syncthreads();
  float acc = 0.f;
  if (ok && lane < DOUT) {
    acc = y[(size_t)v * DOUT + lane];
    const float* Wk = W + (size_t)k * DIN * DOUT + lane;
    #pragma unroll 2
    for (int f = 0; f < DIN; ++f) acc += h[wv][f] * Wk[(size_t)f * DOUT];
  }
  if (FINAL) {
    float val = (ok && lane < DOUT) ? fmaxf(acc, 0.f) : 0.f;
    float ss = val * val;
    #pragma unroll
    for (int off = 32; off > 0; off >>= 1) ss += __shfl_xor(ss, off, 64);
    float scale = 1.f / fmaxf(sqrtf(ss), 1e-12f);
    if (ok && lane < DOUT) Xout[(size_t)v * DOUT + lane] = val * scale;
  } else {
    if (ok && lane < DOUT) y[(size_t)v * DOUT + lane] = acc;
  }
}

// hierarchical segment-max: block-local LDS max over 256 contiguous nodes
// (gids contiguous in this dataset; out-of-range rel falls back to a direct
// global atomic, so correctness holds for arbitrary gid). Values are >= 0
// post relu+l2norm, so uint atomicMax == float max; rep must be zeroed.
__global__ void segmax_kernel(const float* __restrict__ X, const int* __restrict__ gid,
                              float* __restrict__ rep, int n, int row_off) {
  __shared__ float tab[4][45];
  __shared__ int gids[256];
  int t = threadIdx.x;
  for (int i = t; i < 4 * 45; i += 256) ((float*)tab)[i] = 0.f;
  int v0 = blockIdx.x * 256;
  int vend = v0 + 256; if (vend > n) vend = n;
  int nv = vend - v0;
  if (t < nv) gids[t] = gid[v0 + t];
  __syncthreads();
  int g0 = gids[0];
  int total = nv * 45;
  for (int i = t; i < total; i += 256) {
    int vl = i / 45, j = i - vl * 45;
    float val = X[(size_t)(v0 + vl) * 45 + j];
    int rel = gids[vl] - g0;
    if (rel >= 0 && rel < 4)
      atomicMax((unsigned int*)&tab[rel][j], __float_as_uint(val));
    else
      atomicMax((unsigned int*)&rep[(size_t)(row_off + gids[vl]) * 45 + j], __float_as_uint(val));
  }
  __syncthreads();
  for (int i = t; i < 4 * 45; i += 256) {
    float val = ((float*)tab)[i];
    if (val > 0.f) {
      int rel = i / 45, j = i - rel * 45;
      atomicMax((unsigned int*)&rep[(size_t)(row_off + g0 + rel) * 45 + j], __float_as_uint(val));
    }
  }
}

// ---------------- attention ----------------

__global__ void qkv_kernel(const float* __restrict__ rep, const float* __restrict__ w,
                           const float* __restrict__ b, float* __restrict__ qkv) {
  int i = blockIdx.x;      // 0..129
  int t = threadIdx.x;     // 256
  __shared__ float sr[45];
  if (t < 45) sr[t] = (i < 65) ? rep[(size_t)i * 45 + t] : 0.f;
  __syncthreads();
  if (t < 135) {
    float acc = b[t];
    #pragma unroll 5
    for (int d = 0; d < 45; ++d) acc += sr[d] * w[d * 135 + t];
    qkv[(size_t)i * 135 + t] = acc;
  }
}

__global__ void attn_kernel(const float* __restrict__ qkv, const float* __restrict__ proj_w,
                            const float* __restrict__ proj_b, float* __restrict__ ctx) {
  int i = blockIdx.x;     // query row
  int t = threadIdx.x;    // 256
  __shared__ float q[45];
  __shared__ float p[130];
  __shared__ float red[256];
  __shared__ float ao[45];
  if (t < 45) q[t] = qkv[(size_t)i * 135 + t];
  __syncthreads();
  float s = -1e30f;
  if (t < 130) {
    int j = t;
    float dot = 0.f;
    #pragma unroll 5
    for (int d = 0; d < 45; ++d) dot += q[d] * qkv[(size_t)j * 135 + 45 + d];
    dot *= 0.14907119849998599f;  // 45^-0.5
    bool mz;  // mask == 0 ?
    if (i == 64 && j == 64) mz = true;
    else if (i == 64 || j == 64) mz = false;
    else mz = !(i == j && i < 65);
    s = mz ? -1e9f : dot;
  }
  red[t] = s;
  __syncthreads();
  #pragma unroll
  for (int off = 128; off > 0; off >>= 1) {
    if (t < off) red[t] = fmaxf(red[t], red[t + off]);
    __syncthreads();
  }
  float mx = red[0];
  __syncthreads();
  float e = (t < 130) ? expf(s - mx) : 0.f;
  red[t] = e;
  __syncthreads();
  #pragma unroll
  for (int off = 128; off > 0; off >>= 1) {
    if (t < off) red[t] += red[t + off];
    __syncthreads();
  }
  float denom = red[0];
  __syncthreads();
  if (t < 130) p[t] = e / denom;
  __syncthreads();
  if (t < 45) {
    float acc = 0.f;
    for (int j = 0; j < 130; ++j) acc += p[j] * qkv[(size_t)j * 135 + 90 + t];
    ao[t] = acc;
  }
  __syncthreads();
  if (t < 45) {
    float pr = proj_b[t];
    #pragma unroll 5
    for (int e2 = 0; e2 < 45; ++e2) pr += ao[e2] * proj_w[e2 * 45 + t];
    ctx[(size_t)i * 45 + t] = pr;
  }
}

// ---------------- head MLP ----------------

__global__ void bias_init_kernel(const float* __restrict__ b, float* __restrict__ out, int n) {
  int i = blockIdx.x * 256 + threadIdx.x;
  if (i < n) out[i] = b[i];
}

template<bool RELU_IN>
__global__ void fc_splitk_kernel(const float* __restrict__ x, const float* __restrict__ W,
                                 float* __restrict__ out, int nin, int nout, int kchunk) {
  __shared__ float xs[1024];
  int k0 = blockIdx.y * kchunk;
  int k1 = k0 + kchunk; if (k1 > nin) k1 = nin;
  int len = k1 - k0;
  for (int i = threadIdx.x; i < len; i += blockDim.x) {
    float v = x[k0 + i];
    xs[i] = RELU_IN ? fmaxf(v, 0.f) : v;
  }
  __syncthreads();
  int j = blockIdx.x * blockDim.x + threadIdx.x;
  if (j < nout) {
    float acc = 0.f;
    const float* Wp = W + (size_t)k0 * nout + j;
    for (int i = 0; i < len; ++i) acc += xs[i] * Wp[(size_t)i * nout];
    atomicAdd(&out[j], acc);
  }
}

__global__ void final_fc_kernel(const float* __restrict__ x, const float* __restrict__ W,
                                const float* __restrict__ b, float* __restrict__ out) {
  __shared__ float red[512];
  int t = threadIdx.x;
  float acc = 0.f;
  if (t < 500) acc = fmaxf(x[t], 0.f) * W[t];
  red[t] = acc;
  __syncthreads();
  #pragma unroll
  for (int off = 256; off > 0; off >>= 1) {
    if (t < off) red[t] += red[t + off];
    __syncthreads();
  }
  if (t == 0) {
    float z = red[0] + b[0];
    out[0] = 1.f / (1.f + expf(-z));
  }
}

// ---------------- host-side orchestration ----------------

struct GnnBufs {
  float *A, *B, *X, *Y, *nrm;
  int *cnt, *cur, *rp, *col, *bsum;
};

template<int DIN, int DOUT>
void run_layer(const float* xin, const GnnBufs& g, const float* W, const float* b,
               int n, hipStream_t st) {
  int nb = (n + 3) / 4;
  init_gemm_kernel<DIN, DOUT><<<nb, 256, 0, st>>>(xin, g.nrm, W, b, g.A, g.Y, n);
  const float* gin = g.A;
  float* gout = g.B;
  for (int k = 1; k <= 4; ++k) {
    if (k < 4)
      fused_hop_kernel<DIN, DOUT, true, false><<<nb, 256, 0, st>>>(gin, g.rp, g.col, g.nrm, W, gout, g.Y, g.X, k, n);
    else
      fused_hop_kernel<DIN, DOUT, false, true><<<nb, 256, 0, st>>>(gin, g.rp, g.col, g.nrm, W, gout, g.Y, g.X, 4, n);
    float* t = (float*)gin; gin = gout; gout = t;
  }
}

void build_csr(const int* src, const int* dst, const GnnBufs& g, int n, int e, hipStream_t st) {
  hipMemsetAsync(g.cnt, 0, (size_t)n * 4, st);
  hipMemsetAsync(g.cur, 0, (size_t)n * 4, st);
  hist_kernel<<<(e + 255) / 256, 256, 0, st>>>(dst, g.cnt, e);
  int nb1 = (n + 1023) / 1024;
  scan1_kernel<<<nb1, 256, 0, st>>>(g.cnt, g.rp, g.bsum, g.nrm, n);
  scan2_kernel<<<1, 256, 0, st>>>(g.bsum, nb1, g.rp + n);
  scan3_kernel<<<(n + 255) / 256, 256, 0, st>>>(g.rp, g.bsum, n);
  scatter_kernel<<<(e + 255) / 256, 256, 0, st>>>(src, dst, g.rp, g.cur, g.col, e);
}

} // namespace

extern "C" void kernel_launch(void* const* d_in, const int* in_sizes, int n_in,
                              void* d_out, int out_size, void* d_ws, size_t ws_size,
                              hipStream_t stream) {
  (void)in_sizes; (void)n_in; (void)out_size;

  const float* prot_x = (const float*)d_in[0];
  const float* lig_x  = (const float*)d_in[1];
  const float* pW[3] = {(const float*)d_in[2], (const float*)d_in[4], (const float*)d_in[6]};
  const float* pB[3] = {(const float*)d_in[3], (const float*)d_in[5], (const float*)d_in[7]};
  const float* lW[4] = {(const float*)d_in[8], (const float*)d_in[10], (const float*)d_in[12], (const float*)d_in[14]};
  const float* lB[4] = {(const float*)d_in[9], (const float*)d_in[11], (const float*)d_in[13], (const float*)d_in[15]};
  const float* qkv_w = (const float*)d_in[16];
  const float* qkv_b = (const float*)d_in[17];
  const float* proj_w = (const float*)d_in[18];
  const float* proj_b = (const float*)d_in[19];
  const float* h0_w = (const float*)d_in[20];
  const float* h0_b = (const float*)d_in[21];
  const float* h1_w = (const float*)d_in[22];
  const float* h1_b = (const float*)d_in[23];
  const float* h2_w = (const float*)d_in[24];
  const float* h2_b = (const float*)d_in[25];
  const float* fc_w = (const float*)d_in[26];
  const float* fc_b = (const float*)d_in[27];
  const int* prot_src = (const int*)d_in[28];
  const int* prot_dst = (const int*)d_in[29];
  const int* prot_gid = (const int*)d_in[30];
  const int* lig_src  = (const int*)d_in[31];
  const int* lig_dst  = (const int*)d_in[32];
  const int* lig_gid  = (const int*)d_in[33];

  // workspace carve-up
  char* w = (char*)d_ws;
  size_t off = 0;
  auto alloc = [&](size_t bytes) -> void* {
    void* p = w + off;
    off += (bytes + 255) & ~(size_t)255;
    return p;
  };
  float* A   = (float*)alloc((size_t)NPROT * 74 * 4);
  float* Bf  = (float*)alloc((size_t)NPROT * 74 * 4);
  float* X   = (float*)alloc((size_t)NPROT * 50 * 4);
  float* Y   = (float*)alloc((size_t)NPROT * 50 * 4);
  float* nrm = (float*)alloc((size_t)NPROT * 4);
  int* cnt   = (int*)alloc((size_t)NPROT * 4);
  int* cur   = (int*)alloc((size_t)NPROT * 4);
  int* rp    = (int*)alloc(((size_t)NPROT + 1) * 4);
  int* colb  = (int*)alloc((size_t)EPROT * 4);
  int* bsum  = (int*)alloc((size_t)256 * 4);
  float* rep = (float*)alloc((size_t)65 * 45 * 4);
  float* qkvb = (float*)alloc((size_t)130 * 135 * 4);
  float* ctx  = (float*)alloc((size_t)5850 * 4);
  float* hb0  = (float*)alloc((size_t)2000 * 4);
  float* hb1  = (float*)alloc((size_t)1000 * 4);
  float* hb2  = (float*)alloc((size_t)500 * 4);
  if (off > ws_size) return;  // workspace too small: fail loudly via validation

  hipMemsetAsync(rep, 0, (size_t)65 * 45 * 4, stream);

  GnnBufs g{A, Bf, X, Y, nrm, cnt, cur, rp, colb, bsum};

  // ---- protein GNN ----
  build_csr(prot_src, prot_dst, g, NPROT, EPROT, stream);
  run_layer<74, 50>(prot_x, g, pW[0], pB[0], NPROT, stream);
  run_layer<50, 45>(g.X, g, pW[1], pB[1], NPROT, stream);
  run_layer<45, 45>(g.X, g, pW[2], pB[2], NPROT, stream);
  segmax_kernel<<<(NPROT + 255) / 256, 256, 0, stream>>>(g.X, prot_gid, rep, NPROT, 1);

  // ---- ligand GNN (reuses buffers) ----
  build_csr(lig_src, lig_dst, g, NLIG, ELIG, stream);
  run_layer<74, 50>(lig_x, g, lW[0], lB[0], NLIG, stream);
  run_layer<50, 45>(g.X, g, lW[1], lB[1], NLIG, stream);
  run_layer<45, 45>(g.X, g, lW[2], lB[2], NLIG, stream);
  run_layer<45, 45>(g.X, g, lW[3], lB[3], NLIG, stream);
  segmax_kernel<<<(NLIG + 255) / 256, 256, 0, stream>>>(g.X, lig_gid, rep, NLIG, 0);

  // ---- attention ----
  qkv_kernel<<<130, 256, 0, stream>>>(rep, qkv_w, qkv_b, qkvb);
  attn_kernel<<<130, 256, 0, stream>>>(qkvb, proj_w, proj_b, ctx);

  // ---- head MLP (split-K GEMV, bias pre-init, relu folded into next load) ----
  bias_init_kernel<<<8, 256, 0, stream>>>(h0_b, hb0, 2000);
  fc_splitk_kernel<false><<<dim3(8, 8), 256, 0, stream>>>(ctx, h0_w, hb0, 5850, 2000, 732);
  bias_init_kernel<<<4, 256, 0, stream>>>(h1_b, hb1, 1000);
  fc_splitk_kernel<true><<<dim3(4, 4), 256, 0, stream>>>(hb0, h1_w, hb1, 2000, 1000, 500);
  bias_init_kernel<<<2, 256, 0, stream>>>(h2_b, hb2, 500);
  fc_splitk_kernel<true><<<dim3(2, 2), 256, 0, stream>>>(hb1, h2_w, hb2, 1000, 500, 500);
  final_fc_kernel<<<1, 512, 0, stream>>>(hb2, fc_w, fc_b, (float*)d_out);
}

// Round 4
// 2771.274 us; speedup vs baseline: 1.0617x; 1.0617x over previous
//
#include <hip/hip_runtime.h>
#include <hip/hip_fp16.h>
#include <cstddef>
#include <cstdint>

namespace {

constexpr int NPROT = 100000;
constexpr int EPROT = 1600000;
constexpr int NLIG  = 5000;
constexpr int ELIG  = 80000;

// ---------------- CSR construction ----------------

__global__ void hist_kernel(const int* __restrict__ dst, int* __restrict__ cnt, int e) {
  int i = blockIdx.x * 256 + threadIdx.x;
  if (i < e) atomicAdd(&cnt[dst[i]], 1);
}

// per-block (1024 elems) exclusive scan; also computes nrm = max(deg,1)^-0.5
__global__ void scan1_kernel(const int* __restrict__ cnt, int* __restrict__ rp,
                             int* __restrict__ bsum, float* __restrict__ nrm, int n) {
  __shared__ int wsum[4];
  int t = threadIdx.x;
  int base = blockIdx.x * 1024 + t * 4;
  int v0 = 0, v1 = 0, v2 = 0, v3 = 0;
  if (base + 3 < n) {
    int4 val = *(const int4*)(cnt + base);
    v0 = val.x; v1 = val.y; v2 = val.z; v3 = val.w;
  } else if (base < n) {
    v0 = cnt[base];
    if (base + 1 < n) v1 = cnt[base + 1];
    if (base + 2 < n) v2 = cnt[base + 2];
  }
  if (base < n)     nrm[base]     = 1.0f / sqrtf(fmaxf((float)v0, 1.0f));
  if (base + 1 < n) nrm[base + 1] = 1.0f / sqrtf(fmaxf((float)v1, 1.0f));
  if (base + 2 < n) nrm[base + 2] = 1.0f / sqrtf(fmaxf((float)v2, 1.0f));
  if (base + 3 < n) nrm[base + 3] = 1.0f / sqrtf(fmaxf((float)v3, 1.0f));
  int ts = v0 + v1 + v2 + v3;
  int lane = t & 63, wv = t >> 6;
  int incl = ts;
  #pragma unroll
  for (int off = 1; off < 64; off <<= 1) {
    int o = __shfl_up(incl, off, 64);
    if (lane >= off) incl += o;
  }
  if (lane == 63) wsum[wv] = incl;
  __syncthreads();
  int woff = 0;
  #pragma unroll
  for (int i = 0; i < 4; ++i) if (i < wv) woff += wsum[i];
  int excl = woff + incl - ts;
  int o0 = excl, o1 = o0 + v0, o2 = o1 + v1, o3 = o2 + v2;
  if (base + 3 < n) {
    *(int4*)(rp + base) = make_int4(o0, o1, o2, o3);
  } else if (base < n) {
    rp[base] = o0;
    if (base + 1 < n) rp[base + 1] = o1;
    if (base + 2 < n) rp[base + 2] = o2;
  }
  if (t == 255) bsum[blockIdx.x] = woff + incl;  // block total
}

// exclusive scan of <=256 block sums; writes grand total to rp[n]
__global__ void scan2_kernel(int* __restrict__ bsum, int nb, int* __restrict__ rp_end) {
  __shared__ int s[256];
  int t = threadIdx.x;
  int v = (t < nb) ? bsum[t] : 0;
  s[t] = v;
  __syncthreads();
  int val = v;
  for (int off = 1; off < 256; off <<= 1) {
    int add = (t >= off) ? s[t - off] : 0;
    __syncthreads();
    val += add;
    s[t] = val;
    __syncthreads();
  }
  if (t < nb) bsum[t] = val - v;  // exclusive
  if (t == 255) *rp_end = val;    // total
}

__global__ void scan3_kernel(int* __restrict__ rp, const int* __restrict__ bsum, int n) {
  int i = blockIdx.x * 256 + threadIdx.x;
  if (i < n) rp[i] += bsum[i >> 10];
}

__global__ void scatter_kernel(const int* __restrict__ src, const int* __restrict__ dst,
                               const int* __restrict__ rp, int* __restrict__ cur,
                               int* __restrict__ col, int e) {
  int i = blockIdx.x * 256 + threadIdx.x;
  if (i < e) {
    int d = dst[i];
    int p = rp[d] + atomicAdd(&cur[d], 1);
    col[p] = src[i];
  }
}

// ---------------- GNN kernels ----------------
// Carry g_k = norm .* h_k, stored fp16 with padded row stride GS so every row
// is 64B-line aligned (gather touches 1-3 lines/edge instead of 4-6).
// Hop: s_k[v] = sum_{e: dst=v} g_{k-1}[src[e]] (fp32 accum)
//   h_k = norm .* s_k ;  g_k = norm^2 .* s_k
// y = b + sum_k h_k @ W[k*din:(k+1)*din]   (h, y, X all fp32)

// k=0: read x, write g_0 = x*nrm (fp16), y = bias + x @ W_0
template<int DIN, int GS, int DOUT>
__global__ void init_gemm_kernel(const float* __restrict__ x, const float* __restrict__ nrm,
                                 const float* __restrict__ W, const float* __restrict__ bias,
                                 __half* __restrict__ gout, float* __restrict__ y, int n) {
  __shared__ float h[4][DIN];
  int wv = threadIdx.x >> 6, lane = threadIdx.x & 63;
  int v = blockIdx.x * 4 + wv;
  bool ok = (v < n);
  if (ok) {
    float nm = nrm[v];
    const float* xr = x + (size_t)v * DIN;
    for (int f = lane; f < DIN; f += 64) {
      float s = xr[f];
      h[wv][f] = s;
      gout[(size_t)v * GS + f] = __float2half(s * nm);
    }
  }
  __syncthreads();
  if (ok && lane < DOUT) {
    float acc = bias[lane];
    const float* Wk = W + lane;
    #pragma unroll 2
    for (int f = 0; f < DIN; ++f) acc += h[wv][f] * Wk[(size_t)f * DOUT];
    y[(size_t)v * DOUT + lane] = acc;
  }
}

// k>=1: fused gather + scale + (optional g-write) + GEMM accumulate.
// gin immutable (g_{k-1}); gout is a different buffer (ping-pong).
// FINAL: relu + row-l2norm in-register, write X instead of y.
template<int DIN, int GS, int DOUT, bool WRITEG, bool FINAL>
__global__ void fused_hop_kernel(const __half* __restrict__ gin, const int* __restrict__ rp,
                                 const int* __restrict__ col, const float* __restrict__ nrm,
                                 const float* __restrict__ W, __half* __restrict__ gout,
                                 float* __restrict__ y, float* __restrict__ Xout,
                                 int k, int n) {
  __shared__ float h[4][DIN];
  int wv = threadIdx.x >> 6, lane = threadIdx.x & 63;
  int v = blockIdx.x * 4 + wv;
  bool ok = (v < n);
  if (ok) {
    int beg = rp[v], end = rp[v + 1];
    float a0 = 0.f, a1 = 0.f, b0 = 0.f, b1 = 0.f;
    float c0 = 0.f, c1 = 0.f, d0 = 0.f, d1 = 0.f;
    int e = beg;
    for (; e + 4 <= end; e += 4) {
      int s0 = col[e], s1 = col[e + 1], s2 = col[e + 2], s3 = col[e + 3];
      const __half* r0 = gin + (size_t)s0 * GS;
      const __half* r1 = gin + (size_t)s1 * GS;
      const __half* r2 = gin + (size_t)s2 * GS;
      const __half* r3 = gin + (size_t)s3 * GS;
      if (lane < DIN) {
        a0 += __half2float(r0[lane]); b0 += __half2float(r1[lane]);
        c0 += __half2float(r2[lane]); d0 += __half2float(r3[lane]);
      }
      if (DIN > 64) {
        if (lane + 64 < DIN) {
          a1 += __half2float(r0[lane + 64]); b1 += __half2float(r1[lane + 64]);
          c1 += __half2float(r2[lane + 64]); d1 += __half2float(r3[lane + 64]);
        }
      }
    }
    for (; e < end; ++e) {
      int s0 = col[e];
      const __half* r0 = gin + (size_t)s0 * GS;
      if (lane < DIN) a0 += __half2float(r0[lane]);
      if (DIN > 64) { if (lane + 64 < DIN) a1 += __half2float(r0[lane + 64]); }
    }
    a0 += b0 + c0 + d0;
    a1 += b1 + c1 + d1;
    float nm = nrm[v];
    float h0 = a0 * nm, h1 = a1 * nm;
    if (lane < DIN) h[wv][lane] = h0;
    if (DIN > 64) { if (lane + 64 < DIN) h[wv][lane + 64] = h1; }
    if (WRITEG) {
      __half* go = gout + (size_t)v * GS;
      if (lane < DIN) go[lane] = __float2half(h0 * nm);
      if (DIN > 64) { if (lane + 64 < DIN) go[lane + 64] = __float2half(h1 * nm); }
    }
  }
  __syncthreads();
  float acc = 0.f;
  if (ok && lane < DOUT) {
    acc = y[(size_t)v * DOUT + lane];
    const float* Wk = W + (size_t)k * DIN * DOUT + lane;
    #pragma unroll 2
    for (int f = 0; f < DIN; ++f) acc += h[wv][f] * Wk[(size_t)f * DOUT];
  }
  if (FINAL) {
    float val = (ok && lane < DOUT) ? fmaxf(acc, 0.f) : 0.f;
    float ss = val * val;
    #pragma unroll
    for (int off = 32; off > 0; off >>= 1) ss += __shfl_xor(ss, off, 64);
    float scale = 1.f / fmaxf(sqrtf(ss), 1e-12f);
    if (ok && lane < DOUT) Xout[(size_t)v * DOUT + lane] = val * scale;
  } else {
    if (ok && lane < DOUT) y[(size_t)v * DOUT + lane] = acc;
  }
}

// hierarchical segment-max: block-local LDS max over 256 contiguous nodes
// (gids contiguous in this dataset; out-of-range rel falls back to a direct
// global atomic, so correctness holds for arbitrary gid). Values are >= 0
// post relu+l2norm, so uint atomicMax == float max; rep must be zeroed.
__global__ void segmax_kernel(const float* __restrict__ X, const int* __restrict__ gid,
                              float* __restrict__ rep, int n, int row_off) {
  __shared__ float tab[4][45];
  __shared__ int gids[256];
  int t = threadIdx.x;
  for (int i = t; i < 4 * 45; i += 256) ((float*)tab)[i] = 0.f;
  int v0 = blockIdx.x * 256;
  int vend = v0 + 256; if (vend > n) vend = n;
  int nv = vend - v0;
  if (t < nv) gids[t] = gid[v0 + t];
  __syncthreads();
  int g0 = gids[0];
  int total = nv * 45;
  for (int i = t; i < total; i += 256) {
    int vl = i / 45, j = i - vl * 45;
    float val = X[(size_t)(v0 + vl) * 45 + j];
    int rel = gids[vl] - g0;
    if (rel >= 0 && rel < 4)
      atomicMax((unsigned int*)&tab[rel][j], __float_as_uint(val));
    else
      atomicMax((unsigned int*)&rep[(size_t)(row_off + gids[vl]) * 45 + j], __float_as_uint(val));
  }
  __syncthreads();
  for (int i = t; i < 4 * 45; i += 256) {
    float val = ((float*)tab)[i];
    if (val > 0.f) {
      int rel = i / 45, j = i - rel * 45;
      atomicMax((unsigned int*)&rep[(size_t)(row_off + g0 + rel) * 45 + j], __float_as_uint(val));
    }
  }
}

// ---------------- attention ----------------

__global__ void qkv_kernel(const float* __restrict__ rep, const float* __restrict__ w,
                           const float* __restrict__ b, float* __restrict__ qkv) {
  int i = blockIdx.x;      // 0..129
  int t = threadIdx.x;     // 256
  __shared__ float sr[45];
  if (t < 45) sr[t] = (i < 65) ? rep[(size_t)i * 45 + t] : 0.f;
  __syncthreads();
  if (t < 135) {
    float acc = b[t];
    #pragma unroll 5
    for (int d = 0; d < 45; ++d) acc += sr[d] * w[d * 135 + t];
    qkv[(size_t)i * 135 + t] = acc;
  }
}

__global__ void attn_kernel(const float* __restrict__ qkv, const float* __restrict__ proj_w,
                            const float* __restrict__ proj_b, float* __restrict__ ctx) {
  int i = blockIdx.x;     // query row
  int t = threadIdx.x;    // 256
  __shared__ float q[45];
  __shared__ float p[130];
  __shared__ float red[256];
  __shared__ float ao[45];
  if (t < 45) q[t] = qkv[(size_t)i * 135 + t];
  __syncthreads();
  float s = -1e30f;
  if (t < 130) {
    int j = t;
    float dot = 0.f;
    #pragma unroll 5
    for (int d = 0; d < 45; ++d) dot += q[d] * qkv[(size_t)j * 135 + 45 + d];
    dot *= 0.14907119849998599f;  // 45^-0.5
    bool mz;  // mask == 0 ?
    if (i == 64 && j == 64) mz = true;
    else if (i == 64 || j == 64) mz = false;
    else mz = !(i == j && i < 65);
    s = mz ? -1e9f : dot;
  }
  red[t] = s;
  __syncthreads();
  #pragma unroll
  for (int off = 128; off > 0; off >>= 1) {
    if (t < off) red[t] = fmaxf(red[t], red[t + off]);
    __syncthreads();
  }
  float mx = red[0];
  __syncthreads();
  float e = (t < 130) ? expf(s - mx) : 0.f;
  red[t] = e;
  __syncthreads();
  #pragma unroll
  for (int off = 128; off > 0; off >>= 1) {
    if (t < off) red[t] += red[t + off];
    __syncthreads();
  }
  float denom = red[0];
  __syncthreads();
  if (t < 130) p[t] = e / denom;
  __syncthreads();
  if (t < 45) {
    float acc = 0.f;
    for (int j = 0; j < 130; ++j) acc += p[j] * qkv[(size_t)j * 135 + 90 + t];
    ao[t] = acc;
  }
  __syncthreads();
  if (t < 45) {
    float pr = proj_b[t];
    #pragma unroll 5
    for (int e2 = 0; e2 < 45; ++e2) pr += ao[e2] * proj_w[e2 * 45 + t];
    ctx[(size_t)i * 45 + t] = pr;
  }
}

// ---------------- head MLP ----------------

__global__ void bias_init_kernel(const float* __restrict__ b, float* __restrict__ out, int n) {
  int i = blockIdx.x * 256 + threadIdx.x;
  if (i < n) out[i] = b[i];
}

template<bool RELU_IN>
__global__ void fc_splitk_kernel(const float* __restrict__ x, const float* __restrict__ W,
                                 float* __restrict__ out, int nin, int nout, int kchunk) {
  __shared__ float xs[1024];
  int k0 = blockIdx.y * kchunk;
  int k1 = k0 + kchunk; if (k1 > nin) k1 = nin;
  int len = k1 - k0;
  for (int i = threadIdx.x; i < len; i += blockDim.x) {
    float v = x[k0 + i];
    xs[i] = RELU_IN ? fmaxf(v, 0.f) : v;
  }
  __syncthreads();
  int j = blockIdx.x * blockDim.x + threadIdx.x;
  if (j < nout) {
    float acc = 0.f;
    const float* Wp = W + (size_t)k0 * nout + j;
    for (int i = 0; i < len; ++i) acc += xs[i] * Wp[(size_t)i * nout];
    atomicAdd(&out[j], acc);
  }
}

__global__ void final_fc_kernel(const float* __restrict__ x, const float* __restrict__ W,
                                const float* __restrict__ b, float* __restrict__ out) {
  __shared__ float red[512];
  int t = threadIdx.x;
  float acc = 0.f;
  if (t < 500) acc = fmaxf(x[t], 0.f) * W[t];
  red[t] = acc;
  __syncthreads();
  #pragma unroll
  for (int off = 256; off > 0; off >>= 1) {
    if (t < off) red[t] += red[t + off];
    __syncthreads();
  }
  if (t == 0) {
    float z = red[0] + b[0];
    out[0] = 1.f / (1.f + expf(-z));
  }
}

// ---------------- host-side orchestration ----------------

struct GnnBufs {
  __half *A, *B;
  float *X, *Y, *nrm;
  int *cnt, *cur, *rp, *col, *bsum;
};

template<int DIN, int GS, int DOUT>
void run_layer(const float* xin, const GnnBufs& g, const float* W, const float* b,
               int n, hipStream_t st) {
  int nb = (n + 3) / 4;
  init_gemm_kernel<DIN, GS, DOUT><<<nb, 256, 0, st>>>(xin, g.nrm, W, b, g.A, g.Y, n);
  const __half* gin = g.A;
  __half* gout = g.B;
  for (int k = 1; k <= 4; ++k) {
    if (k < 4)
      fused_hop_kernel<DIN, GS, DOUT, true, false><<<nb, 256, 0, st>>>(gin, g.rp, g.col, g.nrm, W, gout, g.Y, g.X, k, n);
    else
      fused_hop_kernel<DIN, GS, DOUT, false, true><<<nb, 256, 0, st>>>(gin, g.rp, g.col, g.nrm, W, gout, g.Y, g.X, 4, n);
    __half* t = (__half*)gin; gin = gout; gout = t;
  }
}

void build_csr(const int* src, const int* dst, const GnnBufs& g, int n, int e, hipStream_t st) {
  hipMemsetAsync(g.cnt, 0, (size_t)n * 4, st);
  hipMemsetAsync(g.cur, 0, (size_t)n * 4, st);
  hist_kernel<<<(e + 255) / 256, 256, 0, st>>>(dst, g.cnt, e);
  int nb1 = (n + 1023) / 1024;
  scan1_kernel<<<nb1, 256, 0, st>>>(g.cnt, g.rp, g.bsum, g.nrm, n);
  scan2_kernel<<<1, 256, 0, st>>>(g.bsum, nb1, g.rp + n);
  scan3_kernel<<<(n + 255) / 256, 256, 0, st>>>(g.rp, g.bsum, n);
  scatter_kernel<<<(e + 255) / 256, 256, 0, st>>>(src, dst, g.rp, g.cur, g.col, e);
}

} // namespace

extern "C" void kernel_launch(void* const* d_in, const int* in_sizes, int n_in,
                              void* d_out, int out_size, void* d_ws, size_t ws_size,
                              hipStream_t stream) {
  (void)in_sizes; (void)n_in; (void)out_size;

  const float* prot_x = (const float*)d_in[0];
  const float* lig_x  = (const float*)d_in[1];
  const float* pW[3] = {(const float*)d_in[2], (const float*)d_in[4], (const float*)d_in[6]};
  const float* pB[3] = {(const float*)d_in[3], (const float*)d_in[5], (const float*)d_in[7]};
  const float* lW[4] = {(const float*)d_in[8], (const float*)d_in[10], (const float*)d_in[12], (const float*)d_in[14]};
  const float* lB[4] = {(const float*)d_in[9], (const float*)d_in[11], (const float*)d_in[13], (const float*)d_in[15]};
  const float* qkv_w = (const float*)d_in[16];
  const float* qkv_b = (const float*)d_in[17];
  const float* proj_w = (const float*)d_in[18];
  const float* proj_b = (const float*)d_in[19];
  const float* h0_w = (const float*)d_in[20];
  const float* h0_b = (const float*)d_in[21];
  const float* h1_w = (const float*)d_in[22];
  const float* h1_b = (const float*)d_in[23];
  const float* h2_w = (const float*)d_in[24];
  const float* h2_b = (const float*)d_in[25];
  const float* fc_w = (const float*)d_in[26];
  const float* fc_b = (const float*)d_in[27];
  const int* prot_src = (const int*)d_in[28];
  const int* prot_dst = (const int*)d_in[29];
  const int* prot_gid = (const int*)d_in[30];
  const int* lig_src  = (const int*)d_in[31];
  const int* lig_dst  = (const int*)d_in[32];
  const int* lig_gid  = (const int*)d_in[33];

  // workspace carve-up
  char* w = (char*)d_ws;
  size_t off = 0;
  auto alloc = [&](size_t bytes) -> void* {
    void* p = w + off;
    off += (bytes + 255) & ~(size_t)255;
    return p;
  };
  __half* A  = (__half*)alloc((size_t)NPROT * 96 * 2);   // fp16 g ping
  __half* Bf = (__half*)alloc((size_t)NPROT * 96 * 2);   // fp16 g pong
  float* X   = (float*)alloc((size_t)NPROT * 50 * 4);
  float* Y   = (float*)alloc((size_t)NPROT * 50 * 4);
  float* nrm = (float*)alloc((size_t)NPROT * 4);
  int* cnt   = (int*)alloc((size_t)NPROT * 4);
  int* cur   = (int*)alloc((size_t)NPROT * 4);
  int* rp    = (int*)alloc(((size_t)NPROT + 1) * 4);
  int* colb  = (int*)alloc((size_t)EPROT * 4);
  int* bsum  = (int*)alloc((size_t)256 * 4);
  float* rep = (float*)alloc((size_t)65 * 45 * 4);
  float* qkvb = (float*)alloc((size_t)130 * 135 * 4);
  float* ctx  = (float*)alloc((size_t)5850 * 4);
  float* hb0  = (float*)alloc((size_t)2000 * 4);
  float* hb1  = (float*)alloc((size_t)1000 * 4);
  float* hb2  = (float*)alloc((size_t)500 * 4);
  if (off > ws_size) return;  // workspace too small: fail loudly via validation

  hipMemsetAsync(rep, 0, (size_t)65 * 45 * 4, stream);

  GnnBufs g{A, Bf, X, Y, nrm, cnt, cur, rp, colb, bsum};

  // ---- protein GNN ----
  build_csr(prot_src, prot_dst, g, NPROT, EPROT, stream);
  run_layer<74, 96, 50>(prot_x, g, pW[0], pB[0], NPROT, stream);
  run_layer<50, 64, 45>(g.X, g, pW[1], pB[1], NPROT, stream);
  run_layer<45, 64, 45>(g.X, g, pW[2], pB[2], NPROT, stream);
  segmax_kernel<<<(NPROT + 255) / 256, 256, 0, stream>>>(g.X, prot_gid, rep, NPROT, 1);

  // ---- ligand GNN (reuses buffers) ----
  build_csr(lig_src, lig_dst, g, NLIG, ELIG, stream);
  run_layer<74, 96, 50>(lig_x, g, lW[0], lB[0], NLIG, stream);
  run_layer<50, 64, 45>(g.X, g, lW[1], lB[1], NLIG, stream);
  run_layer<45, 64, 45>(g.X, g, lW[2], lB[2], NLIG, stream);
  run_layer<45, 64, 45>(g.X, g, lW[3], lB[3], NLIG, stream);
  segmax_kernel<<<(NLIG + 255) / 256, 256, 0, stream>>>(g.X, lig_gid, rep, NLIG, 0);

  // ---- attention ----
  qkv_kernel<<<130, 256, 0, stream>>>(rep, qkv_w, qkv_b, qkvb);
  attn_kernel<<<130, 256, 0, stream>>>(qkvb, proj_w, proj_b, ctx);

  // ---- head MLP (split-K GEMV, bias pre-init, relu folded into next load) ----
  bias_init_kernel<<<8, 256, 0, stream>>>(h0_b, hb0, 2000);
  fc_splitk_kernel<false><<<dim3(8, 8), 256, 0, stream>>>(ctx, h0_w, hb0, 5850, 2000, 732);
  bias_init_kernel<<<4, 256, 0, stream>>>(h1_b, hb1, 1000);
  fc_splitk_kernel<true><<<dim3(4, 4), 256, 0, stream>>>(hb0, h1_w, hb1, 2000, 1000, 500);
  bias_init_kernel<<<2, 256, 0, stream>>>(h2_b, hb2, 500);
  fc_splitk_kernel<true><<<dim3(2, 2), 256, 0, stream>>>(hb1, h2_w, hb2, 1000, 500, 500);
  final_fc_kernel<<<1, 512, 0, stream>>>(hb2, fc_w, fc_b, (float*)d_out);
}

// Round 5
// 2708.543 us; speedup vs baseline: 1.0863x; 1.0232x over previous
//
#include <hip/hip_runtime.h>
#include <hip/hip_fp16.h>
#include <cstddef>
#include <cstdint>

namespace {

constexpr int NPROT = 100000;
constexpr int EPROT = 1600000;
constexpr int NLIG  = 5000;
constexpr int ELIG  = 80000;

// ---------------- CSR construction ----------------

__global__ void hist_kernel(const int* __restrict__ dst, int* __restrict__ cnt, int e) {
  int i = blockIdx.x * 256 + threadIdx.x;
  if (i < e) atomicAdd(&cnt[dst[i]], 1);
}

// per-block (1024 elems) exclusive scan; also computes nrm = max(deg,1)^-0.5
__global__ void scan1_kernel(const int* __restrict__ cnt, int* __restrict__ rp,
                             int* __restrict__ bsum, float* __restrict__ nrm, int n) {
  __shared__ int wsum[4];
  int t = threadIdx.x;
  int base = blockIdx.x * 1024 + t * 4;
  int v0 = 0, v1 = 0, v2 = 0, v3 = 0;
  if (base + 3 < n) {
    int4 val = *(const int4*)(cnt + base);
    v0 = val.x; v1 = val.y; v2 = val.z; v3 = val.w;
  } else if (base < n) {
    v0 = cnt[base];
    if (base + 1 < n) v1 = cnt[base + 1];
    if (base + 2 < n) v2 = cnt[base + 2];
  }
  if (base < n)     nrm[base]     = 1.0f / sqrtf(fmaxf((float)v0, 1.0f));
  if (base + 1 < n) nrm[base + 1] = 1.0f / sqrtf(fmaxf((float)v1, 1.0f));
  if (base + 2 < n) nrm[base + 2] = 1.0f / sqrtf(fmaxf((float)v2, 1.0f));
  if (base + 3 < n) nrm[base + 3] = 1.0f / sqrtf(fmaxf((float)v3, 1.0f));
  int ts = v0 + v1 + v2 + v3;
  int lane = t & 63, wv = t >> 6;
  int incl = ts;
  #pragma unroll
  for (int off = 1; off < 64; off <<= 1) {
    int o = __shfl_up(incl, off, 64);
    if (lane >= off) incl += o;
  }
  if (lane == 63) wsum[wv] = incl;
  __syncthreads();
  int woff = 0;
  #pragma unroll
  for (int i = 0; i < 4; ++i) if (i < wv) woff += wsum[i];
  int excl = woff + incl - ts;
  int o0 = excl, o1 = o0 + v0, o2 = o1 + v1, o3 = o2 + v2;
  if (base + 3 < n) {
    *(int4*)(rp + base) = make_int4(o0, o1, o2, o3);
  } else if (base < n) {
    rp[base] = o0;
    if (base + 1 < n) rp[base + 1] = o1;
    if (base + 2 < n) rp[base + 2] = o2;
  }
  if (t == 255) bsum[blockIdx.x] = woff + incl;  // block total
}

// exclusive scan of <=256 block sums; writes grand total to rp[n]
__global__ void scan2_kernel(int* __restrict__ bsum, int nb, int* __restrict__ rp_end) {
  __shared__ int s[256];
  int t = threadIdx.x;
  int v = (t < nb) ? bsum[t] : 0;
  s[t] = v;
  __syncthreads();
  int val = v;
  for (int off = 1; off < 256; off <<= 1) {
    int add = (t >= off) ? s[t - off] : 0;
    __syncthreads();
    val += add;
    s[t] = val;
    __syncthreads();
  }
  if (t < nb) bsum[t] = val - v;  // exclusive
  if (t == 255) *rp_end = val;    // total
}

__global__ void scan3_kernel(int* __restrict__ rp, const int* __restrict__ bsum, int n) {
  int i = blockIdx.x * 256 + threadIdx.x;
  if (i < n) rp[i] += bsum[i >> 10];
}

__global__ void scatter_kernel(const int* __restrict__ src, const int* __restrict__ dst,
                               const int* __restrict__ rp, int* __restrict__ cur,
                               int* __restrict__ col, int e) {
  int i = blockIdx.x * 256 + threadIdx.x;
  if (i < e) {
    int d = dst[i];
    int p = rp[d] + atomicAdd(&cur[d], 1);
    col[p] = src[i];
  }
}

// ---------------- GNN kernels ----------------
// Carry g_k = norm .* h_k, stored fp16 with padded row stride GS (64B-aligned
// rows -> 2-3 lines per gather). Hop: s_k[v] = sum_{dst=v} g_{k-1}[src]
// (fp32 accum); h_k = nrm*s_k; g_k = nrm^2*s_k; y += h_k @ W_k.
// One wave per node, lane = feature. No LDS, no barriers: col indices are
// register-cached (one coalesced load per 64 edges, __shfl to broadcast),
// row loads issued in independent batches of 8 for MLP; the GEMM broadcast
// uses __shfl instead of LDS.

// k=0: read x, write g_0 = x*nrm (fp16), y = bias + x @ W_0
template<int DIN, int GS, int DOUT>
__global__ void init_gemm_kernel(const float* __restrict__ x, const float* __restrict__ nrm,
                                 const float* __restrict__ W, const float* __restrict__ bias,
                                 __half* __restrict__ gout, float* __restrict__ y, int n) {
  int lane = threadIdx.x & 63;
  int v = blockIdx.x * 4 + (threadIdx.x >> 6);
  if (v >= n) return;
  float nm = nrm[v];
  const float* xr = x + (size_t)v * DIN;
  float hA = (lane < DIN) ? xr[lane] : 0.f;
  float hB = 0.f;
  if constexpr (DIN > 64) { if (lane + 64 < DIN) hB = xr[lane + 64]; }
  __half* go = gout + (size_t)v * GS;
  if (lane < DIN) go[lane] = __float2half(hA * nm);
  if constexpr (DIN > 64) { if (lane + 64 < DIN) go[lane + 64] = __float2half(hB * nm); }
  int cl = (lane < DOUT) ? lane : 0;
  float acc = bias[cl];
  const float* Wk = W + cl;
  #pragma unroll
  for (int f = 0; f < DIN; ++f) {
    float hf = (f < 64) ? __shfl(hA, f, 64) : __shfl(hB, f - 64, 64);
    acc += hf * Wk[(size_t)f * DOUT];
  }
  if (lane < DOUT) y[(size_t)v * DOUT + lane] = acc;
}

// k>=1: fused gather + scale + (optional g-write) + GEMM accumulate.
// FINAL: relu + row-l2norm in-register, write X instead of y.
template<int DIN, int GS, int DOUT, bool WRITEG, bool FINAL>
__global__ void fused_hop_kernel(const __half* __restrict__ gin, const int* __restrict__ rp,
                                 const int* __restrict__ col, const float* __restrict__ nrm,
                                 const float* __restrict__ W, __half* __restrict__ gout,
                                 float* __restrict__ y, float* __restrict__ Xout,
                                 int k, int n) {
  int lane = threadIdx.x & 63;
  int v = blockIdx.x * 4 + (threadIdx.x >> 6);
  if (v >= n) return;
  int beg = rp[v], end = rp[v + 1];
  float a0 = 0.f, a1 = 0.f;
  for (int base = beg; base < end; base += 64) {
    int m = end - base; if (m > 64) m = 64;
    int myc = (lane < m) ? col[base + lane] : 0;   // 64 edge indices per load
    int j = 0;
    for (; j + 8 <= m; j += 8) {
      int ss[8];
      float t0[8], t1[8];
      #pragma unroll
      for (int u = 0; u < 8; ++u) ss[u] = __shfl(myc, j + u, 64);
      #pragma unroll
      for (int u = 0; u < 8; ++u) {
        const __half* r = gin + (size_t)ss[u] * GS;
        t0[u] = (lane < DIN) ? __half2float(r[lane]) : 0.f;
        if constexpr (DIN > 64) t1[u] = (lane + 64 < DIN) ? __half2float(r[lane + 64]) : 0.f;
      }
      #pragma unroll
      for (int u = 0; u < 8; ++u) {
        a0 += t0[u];
        if constexpr (DIN > 64) a1 += t1[u];
      }
    }
    for (; j < m; ++j) {
      int s = __shfl(myc, j, 64);
      const __half* r = gin + (size_t)s * GS;
      if (lane < DIN) a0 += __half2float(r[lane]);
      if constexpr (DIN > 64) { if (lane + 64 < DIN) a1 += __half2float(r[lane + 64]); }
    }
  }
  float nm = nrm[v];
  float hA = a0 * nm, hB = a1 * nm;
  if (WRITEG) {
    __half* go = gout + (size_t)v * GS;
    if (lane < DIN) go[lane] = __float2half(hA * nm);
    if constexpr (DIN > 64) { if (lane + 64 < DIN) go[lane + 64] = __float2half(hB * nm); }
  }
  int cl = (lane < DOUT) ? lane : 0;
  float acc = 0.f;
  if (lane < DOUT) acc = y[(size_t)v * DOUT + lane];
  const float* Wk = W + (size_t)k * DIN * DOUT + cl;
  #pragma unroll
  for (int f = 0; f < DIN; ++f) {
    float hf = (f < 64) ? __shfl(hA, f, 64) : __shfl(hB, f - 64, 64);
    acc += hf * Wk[(size_t)f * DOUT];
  }
  if constexpr (FINAL) {
    float val = (lane < DOUT) ? fmaxf(acc, 0.f) : 0.f;
    float ss2 = val * val;
    #pragma unroll
    for (int off2 = 32; off2 > 0; off2 >>= 1) ss2 += __shfl_xor(ss2, off2, 64);
    float scale = 1.f / fmaxf(sqrtf(ss2), 1e-12f);
    if (lane < DOUT) Xout[(size_t)v * DOUT + lane] = val * scale;
  } else {
    if (lane < DOUT) y[(size_t)v * DOUT + lane] = acc;
  }
}

// hierarchical segment-max: block-local LDS max over 256 contiguous nodes
// (gids contiguous in this dataset; out-of-range rel falls back to a direct
// global atomic, so correctness holds for arbitrary gid). Values are >= 0
// post relu+l2norm, so uint atomicMax == float max; rep must be zeroed.
__global__ void segmax_kernel(const float* __restrict__ X, const int* __restrict__ gid,
                              float* __restrict__ rep, int n, int row_off) {
  __shared__ float tab[4][45];
  __shared__ int gids[256];
  int t = threadIdx.x;
  for (int i = t; i < 4 * 45; i += 256) ((float*)tab)[i] = 0.f;
  int v0 = blockIdx.x * 256;
  int vend = v0 + 256; if (vend > n) vend = n;
  int nv = vend - v0;
  if (t < nv) gids[t] = gid[v0 + t];
  __syncthreads();
  int g0 = gids[0];
  int total = nv * 45;
  for (int i = t; i < total; i += 256) {
    int vl = i / 45, j = i - vl * 45;
    float val = X[(size_t)(v0 + vl) * 45 + j];
    int rel = gids[vl] - g0;
    if (rel >= 0 && rel < 4)
      atomicMax((unsigned int*)&tab[rel][j], __float_as_uint(val));
    else
      atomicMax((unsigned int*)&rep[(size_t)(row_off + gids[vl]) * 45 + j], __float_as_uint(val));
  }
  __syncthreads();
  for (int i = t; i < 4 * 45; i += 256) {
    float val = ((float*)tab)[i];
    if (val > 0.f) {
      int rel = i / 45, j = i - rel * 45;
      atomicMax((unsigned int*)&rep[(size_t)(row_off + g0 + rel) * 45 + j], __float_as_uint(val));
    }
  }
}

// ---------------- attention ----------------

__global__ void qkv_kernel(const float* __restrict__ rep, const float* __restrict__ w,
                           const float* __restrict__ b, float* __restrict__ qkv) {
  int i = blockIdx.x;      // 0..129
  int t = threadIdx.x;     // 256
  __shared__ float sr[45];
  if (t < 45) sr[t] = (i < 65) ? rep[(size_t)i * 45 + t] : 0.f;
  __syncthreads();
  if (t < 135) {
    float acc = b[t];
    #pragma unroll 5
    for (int d = 0; d < 45; ++d) acc += sr[d] * w[d * 135 + t];
    qkv[(size_t)i * 135 + t] = acc;
  }
}

__global__ void attn_kernel(const float* __restrict__ qkv, const float* __restrict__ proj_w,
                            const float* __restrict__ proj_b, float* __restrict__ ctx) {
  int i = blockIdx.x;     // query row
  int t = threadIdx.x;    // 256
  __shared__ float q[45];
  __shared__ float p[130];
  __shared__ float red[256];
  __shared__ float ao[45];
  if (t < 45) q[t] = qkv[(size_t)i * 135 + t];
  __syncthreads();
  float s = -1e30f;
  if (t < 130) {
    int j = t;
    float dot = 0.f;
    #pragma unroll 5
    for (int d = 0; d < 45; ++d) dot += q[d] * qkv[(size_t)j * 135 + 45 + d];
    dot *= 0.14907119849998599f;  // 45^-0.5
    bool mz;  // mask == 0 ?
    if (i == 64 && j == 64) mz = true;
    else if (i == 64 || j == 64) mz = false;
    else mz = !(i == j && i < 65);
    s = mz ? -1e9f : dot;
  }
  red[t] = s;
  __syncthreads();
  #pragma unroll
  for (int off = 128; off > 0; off >>= 1) {
    if (t < off) red[t] = fmaxf(red[t], red[t + off]);
    __syncthreads();
  }
  float mx = red[0];
  __syncthreads();
  float e = (t < 130) ? expf(s - mx) : 0.f;
  red[t] = e;
  __syncthreads();
  #pragma unroll
  for (int off = 128; off > 0; off >>= 1) {
    if (t < off) red[t] += red[t + off];
    __syncthreads();
  }
  float denom = red[0];
  __syncthreads();
  if (t < 130) p[t] = e / denom;
  __syncthreads();
  if (t < 45) {
    float acc = 0.f;
    for (int j = 0; j < 130; ++j) acc += p[j] * qkv[(size_t)j * 135 + 90 + t];
    ao[t] = acc;
  }
  __syncthreads();
  if (t < 45) {
    float pr = proj_b[t];
    #pragma unroll 5
    for (int e2 = 0; e2 < 45; ++e2) pr += ao[e2] * proj_w[e2 * 45 + t];
    ctx[(size_t)i * 45 + t] = pr;
  }
}

// ---------------- head MLP ----------------

__global__ void bias_init_kernel(const float* __restrict__ b, float* __restrict__ out, int n) {
  int i = blockIdx.x * 256 + threadIdx.x;
  if (i < n) out[i] = b[i];
}

template<bool RELU_IN>
__global__ void fc_splitk_kernel(const float* __restrict__ x, const float* __restrict__ W,
                                 float* __restrict__ out, int nin, int nout, int kchunk) {
  __shared__ float xs[1024];
  int k0 = blockIdx.y * kchunk;
  int k1 = k0 + kchunk; if (k1 > nin) k1 = nin;
  int len = k1 - k0;
  for (int i = threadIdx.x; i < len; i += blockDim.x) {
    float v = x[k0 + i];
    xs[i] = RELU_IN ? fmaxf(v, 0.f) : v;
  }
  __syncthreads();
  int j = blockIdx.x * blockDim.x + threadIdx.x;
  if (j < nout) {
    float acc = 0.f;
    const float* Wp = W + (size_t)k0 * nout + j;
    for (int i = 0; i < len; ++i) acc += xs[i] * Wp[(size_t)i * nout];
    atomicAdd(&out[j], acc);
  }
}

__global__ void final_fc_kernel(const float* __restrict__ x, const float* __restrict__ W,
                                const float* __restrict__ b, float* __restrict__ out) {
  __shared__ float red[512];
  int t = threadIdx.x;
  float acc = 0.f;
  if (t < 500) acc = fmaxf(x[t], 0.f) * W[t];
  red[t] = acc;
  __syncthreads();
  #pragma unroll
  for (int off = 256; off > 0; off >>= 1) {
    if (t < off) red[t] += red[t + off];
    __syncthreads();
  }
  if (t == 0) {
    float z = red[0] + b[0];
    out[0] = 1.f / (1.f + expf(-z));
  }
}

// ---------------- host-side orchestration ----------------

struct GnnBufs {
  __half *A, *B;
  float *X, *Y, *nrm;
  int *cnt, *cur, *rp, *col, *bsum;
};

template<int DIN, int GS, int DOUT>
void run_layer(const float* xin, const GnnBufs& g, const float* W, const float* b,
               int n, hipStream_t st) {
  int nb = (n + 3) / 4;
  init_gemm_kernel<DIN, GS, DOUT><<<nb, 256, 0, st>>>(xin, g.nrm, W, b, g.A, g.Y, n);
  const __half* gin = g.A;
  __half* gout = g.B;
  for (int k = 1; k <= 4; ++k) {
    if (k < 4)
      fused_hop_kernel<DIN, GS, DOUT, true, false><<<nb, 256, 0, st>>>(gin, g.rp, g.col, g.nrm, W, gout, g.Y, g.X, k, n);
    else
      fused_hop_kernel<DIN, GS, DOUT, false, true><<<nb, 256, 0, st>>>(gin, g.rp, g.col, g.nrm, W, gout, g.Y, g.X, 4, n);
    __half* t = (__half*)gin; gin = gout; gout = t;
  }
}

void build_csr(const int* src, const int* dst, const GnnBufs& g, int n, int e, hipStream_t st) {
  hipMemsetAsync(g.cnt, 0, (size_t)n * 4, st);
  hipMemsetAsync(g.cur, 0, (size_t)n * 4, st);
  hist_kernel<<<(e + 255) / 256, 256, 0, st>>>(dst, g.cnt, e);
  int nb1 = (n + 1023) / 1024;
  scan1_kernel<<<nb1, 256, 0, st>>>(g.cnt, g.rp, g.bsum, g.nrm, n);
  scan2_kernel<<<1, 256, 0, st>>>(g.bsum, nb1, g.rp + n);
  scan3_kernel<<<(n + 255) / 256, 256, 0, st>>>(g.rp, g.bsum, n);
  scatter_kernel<<<(e + 255) / 256, 256, 0, st>>>(src, dst, g.rp, g.cur, g.col, e);
}

} // namespace

extern "C" void kernel_launch(void* const* d_in, const int* in_sizes, int n_in,
                              void* d_out, int out_size, void* d_ws, size_t ws_size,
                              hipStream_t stream) {
  (void)in_sizes; (void)n_in; (void)out_size;

  const float* prot_x = (const float*)d_in[0];
  const float* lig_x  = (const float*)d_in[1];
  const float* pW[3] = {(const float*)d_in[2], (const float*)d_in[4], (const float*)d_in[6]};
  const float* pB[3] = {(const float*)d_in[3], (const float*)d_in[5], (const float*)d_in[7]};
  const float* lW[4] = {(const float*)d_in[8], (const float*)d_in[10], (const float*)d_in[12], (const float*)d_in[14]};
  const float* lB[4] = {(const float*)d_in[9], (const float*)d_in[11], (const float*)d_in[13], (const float*)d_in[15]};
  const float* qkv_w = (const float*)d_in[16];
  const float* qkv_b = (const float*)d_in[17];
  const float* proj_w = (const float*)d_in[18];
  const float* proj_b = (const float*)d_in[19];
  const float* h0_w = (const float*)d_in[20];
  const float* h0_b = (const float*)d_in[21];
  const float* h1_w = (const float*)d_in[22];
  const float* h1_b = (const float*)d_in[23];
  const float* h2_w = (const float*)d_in[24];
  const float* h2_b = (const float*)d_in[25];
  const float* fc_w = (const float*)d_in[26];
  const float* fc_b = (const float*)d_in[27];
  const int* prot_src = (const int*)d_in[28];
  const int* prot_dst = (const int*)d_in[29];
  const int* prot_gid = (const int*)d_in[30];
  const int* lig_src  = (const int*)d_in[31];
  const int* lig_dst  = (const int*)d_in[32];
  const int* lig_gid  = (const int*)d_in[33];

  // workspace carve-up
  char* w = (char*)d_ws;
  size_t off = 0;
  auto alloc = [&](size_t bytes) -> void* {
    void* p = w + off;
    off += (bytes + 255) & ~(size_t)255;
    return p;
  };
  __half* A  = (__half*)alloc((size_t)NPROT * 96 * 2);   // fp16 g ping
  __half* Bf = (__half*)alloc((size_t)NPROT * 96 * 2);   // fp16 g pong
  float* X   = (float*)alloc((size_t)NPROT * 50 * 4);
  float* Y   = (float*)alloc((size_t)NPROT * 50 * 4);
  float* nrm = (float*)alloc((size_t)NPROT * 4);
  int* cnt   = (int*)alloc((size_t)NPROT * 4);
  int* cur   = (int*)alloc((size_t)NPROT * 4);
  int* rp    = (int*)alloc(((size_t)NPROT + 1) * 4);
  int* colb  = (int*)alloc((size_t)EPROT * 4);
  int* bsum  = (int*)alloc((size_t)256 * 4);
  float* rep = (float*)alloc((size_t)65 * 45 * 4);
  float* qkvb = (float*)alloc((size_t)130 * 135 * 4);
  float* ctx  = (float*)alloc((size_t)5850 * 4);
  float* hb0  = (float*)alloc((size_t)2000 * 4);
  float* hb1  = (float*)alloc((size_t)1000 * 4);
  float* hb2  = (float*)alloc((size_t)500 * 4);
  if (off > ws_size) return;  // workspace too small: fail loudly via validation

  hipMemsetAsync(rep, 0, (size_t)65 * 45 * 4, stream);

  GnnBufs g{A, Bf, X, Y, nrm, cnt, cur, rp, colb, bsum};

  // ---- protein GNN ----
  build_csr(prot_src, prot_dst, g, NPROT, EPROT, stream);
  run_layer<74, 96, 50>(prot_x, g, pW[0], pB[0], NPROT, stream);
  run_layer<50, 64, 45>(g.X, g, pW[1], pB[1], NPROT, stream);
  run_layer<45, 64, 45>(g.X, g, pW[2], pB[2], NPROT, stream);
  segmax_kernel<<<(NPROT + 255) / 256, 256, 0, stream>>>(g.X, prot_gid, rep, NPROT, 1);

  // ---- ligand GNN (reuses buffers) ----
  build_csr(lig_src, lig_dst, g, NLIG, ELIG, stream);
  run_layer<74, 96, 50>(lig_x, g, lW[0], lB[0], NLIG, stream);
  run_layer<50, 64, 45>(g.X, g, lW[1], lB[1], NLIG, stream);
  run_layer<45, 64, 45>(g.X, g, lW[2], lB[2], NLIG, stream);
  run_layer<45, 64, 45>(g.X, g, lW[3], lB[3], NLIG, stream);
  segmax_kernel<<<(NLIG + 255) / 256, 256, 0, stream>>>(g.X, lig_gid, rep, NLIG, 0);

  // ---- attention ----
  qkv_kernel<<<130, 256, 0, stream>>>(rep, qkv_w, qkv_b, qkvb);
  attn_kernel<<<130, 256, 0, stream>>>(qkvb, proj_w, proj_b, ctx);

  // ---- head MLP (split-K GEMV, bias pre-init, relu folded into next load) ----
  bias_init_kernel<<<8, 256, 0, stream>>>(h0_b, hb0, 2000);
  fc_splitk_kernel<false><<<dim3(8, 8), 256, 0, stream>>>(ctx, h0_w, hb0, 5850, 2000, 732);
  bias_init_kernel<<<4, 256, 0, stream>>>(h1_b, hb1, 1000);
  fc_splitk_kernel<true><<<dim3(4, 4), 256, 0, stream>>>(hb0, h1_w, hb1, 2000, 1000, 500);
  bias_init_kernel<<<2, 256, 0, stream>>>(h2_b, hb2, 500);
  fc_splitk_kernel<true><<<dim3(2, 2), 256, 0, stream>>>(hb1, h2_w, hb2, 1000, 500, 500);
  final_fc_kernel<<<1, 512, 0, stream>>>(hb2, fc_w, fc_b, (float*)d_out);
}